// Round 4
// baseline (239.152 us; speedup 1.0000x reference)
//
#include <hip/hip_runtime.h>

// Problem constants
#define HW    224
#define IMG   (HW * HW)     // 50176 pixels per image
#define ROW4  (HW / 4)      // 56 float4 per row
#define IMG4  (IMG / 4)     // 12544 float4 per image (= 49 * 256)

// mask = max(1 - 12*acos(c)/pi, 0), c = cos(angle between (pixel-head) and gaze).
// ~205 MB pure writes -> write-BW-bound; straight-line compute hides under it.

__global__ __launch_bounds__(256) void gaze_cone_kernel(
    const float* __restrict__ xy,          // [B,2] gaze direction
    const float* __restrict__ head_point,  // [B,2] pixel coords
    float* __restrict__ out)               // [B,1,224,224]
{
#pragma clang fp contract(off)
    const float SCALE = 3.81971863420548805845f;  // 12/pi (applied after acos)

    const int b = blockIdx.x;              // one block per image

    // Wave-uniform per-image scalars, hoisted out of the loop.
    const float x0 = xy[2 * b];
    const float x1 = xy[2 * b + 1];
    const float h0 = head_point[2 * b];
    const float h1 = head_point[2 * b + 1];

    // xy_norm: same op order as reference (x0*x0 + x1*x1, no fma)
    const float xyn = sqrtf(x0 * x0 + x1 * x1);

    float4* const outb = reinterpret_cast<float4*>(out) + (size_t)b * IMG4;

    // IMG4 = 49 * 256: exactly 49 uniform iterations, no bounds check.
#pragma unroll 2
    for (int rem = threadIdx.x; rem < IMG4; rem += 256) {
        int i  = rem / ROW4;               // row (y)  — magic-mul div by 56
        int k0 = (rem - i * ROW4) * 4;     // first column (x) of this float4

        float dy   = (float)i - h1;
        float dy2  = dy * dy;              // identical rounding to reference
        float dyx1 = dy * x1;

        float4 r;
        float* rp = &r.x;
#pragma unroll
        for (int j = 0; j < 4; ++j) {
            float dx    = (float)(k0 + j) - h0;
            float num   = dx * x0 + dyx1;          // mul, add (contract off)
            float an    = sqrtf(dx * dx + dy2);    // arr_norm
            float denom = an * xyn;
            float dsel  = (denom > 0.0f) ? denom : 1.0f;
            float c     = num / dsel;              // IEEE div
            float theta = acosf(c);                // c>1 -> NaN
            float m     = 1.0f - theta * SCALE;
            // IEEE fmaxf drops NaN -> reproduces jnp.maximum + nan_to_num.
            rp[j] = fmaxf(m, 0.0f);
        }

        outb[rem] = r;                     // coalesced 1 KB/wave stores
    }
}

extern "C" void kernel_launch(void* const* d_in, const int* in_sizes, int n_in,
                              void* d_out, int out_size, void* d_ws, size_t ws_size,
                              hipStream_t stream) {
    const float* xy = (const float*)d_in[0];
    const float* hp = (const float*)d_in[1];
    float* out      = (float*)d_out;

    const int B = in_sizes[0] / 2;   // 1024

    // One block per image: per-batch scalars become loop-invariant uniforms.
    // 1024 blocks x 256 threads = 16 waves/CU — ample for store streaming.
    gaze_cone_kernel<<<B, 256, 0, stream>>>(xy, hp, out);
}

// Round 5
// 237.580 us; speedup vs baseline: 1.0066x; 1.0066x over previous
//
#include <hip/hip_runtime.h>

// Problem constants
#define HW    224
#define IMG   (HW * HW)     // 50176 pixels per image
#define ROW4  (HW / 4)      // 56 float4 per row
#define IMG4  (IMG / 4)     // 12544 float4 per image (= 49 * 256)

// mask = max(1 - (12/pi)*acos(c), 0) is NONZERO only when c > cos(pi/12)=0.965926.
// ~92% of pixels are outside that 15-degree wedge -> wave-uniform early-out:
// cheap div/sqrt-free test (num>0 && num^2 > T^2*xyn^2*d2, T=0.9658 < cos(pi/12),
// margin 1.3e-4 in c >> fp noise) stores zeros; only waves that might touch the
// wedge run the expensive IEEE div + acosf path (bit-identical to round-4 kernel).

__global__ __launch_bounds__(256) void gaze_cone_kernel(
    const float* __restrict__ xy,          // [B,2] gaze direction
    const float* __restrict__ head_point,  // [B,2] pixel coords
    float* __restrict__ out)               // [B,1,224,224]
{
#pragma clang fp contract(off)
    const float SCALE = 3.81971863420548805845f;  // 12/pi (applied after acos)
    const float T2    = 0.9658f * 0.9658f;        // (0.9658)^2, strictly < cos^2(pi/12)

    const int b = blockIdx.x;              // one block per image

    // Wave-uniform per-image scalars, hoisted out of the loop.
    const float x0 = xy[2 * b];
    const float x1 = xy[2 * b + 1];
    const float h0 = head_point[2 * b];
    const float h1 = head_point[2 * b + 1];

    const float xyn2 = x0 * x0 + x1 * x1;  // same op order as reference
    const float xyn  = sqrtf(xyn2);
    const float K    = T2 * xyn2;          // test constant: num^2 > K * d2

    float4* const outb = reinterpret_cast<float4*>(out) + (size_t)b * IMG4;

    // IMG4 = 49 * 256: exactly 49 uniform iterations, no bounds check.
    for (int rem = threadIdx.x; rem < IMG4; rem += 256) {
        int i  = rem / ROW4;               // row (y)  — magic-mul div by 56
        int k0 = (rem - i * ROW4) * 4;     // first column (x) of this float4

        float dy   = (float)i - h1;
        float dy2  = dy * dy;              // identical rounding to reference
        float dyx1 = dy * x1;

        // --- cheap classification: could any of my 4 pixels be nonzero? ---
        float numv[4], d2v[4];
        bool pred = false;
#pragma unroll
        for (int j = 0; j < 4; ++j) {
            float dx = (float)(k0 + j) - h0;
            float nu = dx * x0 + dyx1;     // mul, add (contract off)
            float d2 = dx * dx + dy2;
            numv[j] = nu;
            d2v[j]  = d2;
            pred = pred || (nu > 0.0f && nu * nu > K * d2);
        }

        float4 r;
        if (__any(pred)) {
            // --- precise path (identical numerics to the passing kernel) ---
            float* rp = &r.x;
#pragma unroll
            for (int j = 0; j < 4; ++j) {
                float an    = sqrtf(d2v[j]);          // arr_norm
                float denom = an * xyn;
                float dsel  = (denom > 0.0f) ? denom : 1.0f;
                float c     = numv[j] / dsel;         // IEEE div
                float theta = acosf(c);               // c>1 -> NaN
                float m     = 1.0f - theta * SCALE;
                rp[j] = fmaxf(m, 0.0f);               // NaN -> 0 (nan_to_num)
            }
        } else {
            // Whole wave provably outside the cone: mask is exactly 0.
            r = make_float4(0.0f, 0.0f, 0.0f, 0.0f);
        }

        outb[rem] = r;                     // coalesced 1 KB/wave stores
    }
}

extern "C" void kernel_launch(void* const* d_in, const int* in_sizes, int n_in,
                              void* d_out, int out_size, void* d_ws, size_t ws_size,
                              hipStream_t stream) {
    const float* xy = (const float*)d_in[0];
    const float* hp = (const float*)d_in[1];
    float* out      = (float*)d_out;

    const int B = in_sizes[0] / 2;   // 1024

    // One block per image: per-batch scalars become loop-invariant uniforms.
    gaze_cone_kernel<<<B, 256, 0, stream>>>(xy, hp, out);
}

// Round 9
// 226.210 us; speedup vs baseline: 1.0572x; 1.0503x over previous
//
#include <hip/hip_runtime.h>

// Problem constants
#define HW    224
#define IMG   (HW * HW)     // 50176 pixels per image
#define ROW4  (HW / 4)      // 56 float4 per row
#define IMG4  (IMG / 4)     // 12544 float4 per image (= 49 * 256)

// mask = max(1 - (12/pi)*acos(c), 0), nonzero only for c > cos(pi/12).
// Round-5 lesson: wave early-out alone was null (cone crosses most row-strips;
// ~50% of waves stay slow). This round replaces ocml acosf (~45 instrs) with
// the series acos(1-u) = sqrt(2u)*(1 + u/12 + 3u^2/160): theta error < 6e-6 rad
// over the whole nonzero region (mask err < 2.3e-5 << passing absmax 1.95e-3).
// The IEEE ops producing c (sqrtf, mul, div) are kept BIT-IDENTICAL to the
// passing baseline so the near-ray NaN classification (c>1 -> 0) is unchanged:
// u = 1-c is exact (Sterbenz), u<0 -> v_sqrt(2u)=NaN -> fmaxf -> 0.

__global__ __launch_bounds__(256) void gaze_cone_kernel(
    const float* __restrict__ xy,          // [B,2] gaze direction
    const float* __restrict__ head_point,  // [B,2] pixel coords
    float* __restrict__ out)               // [B,1,224,224]
{
#pragma clang fp contract(off)
    const float SCALE = 3.81971863420548805845f;  // 12/pi
    const float T2    = 0.9658f * 0.9658f;        // strictly < cos^2(pi/12)

    const int b = blockIdx.x;              // one block per image

    const float x0 = xy[2 * b];
    const float x1 = xy[2 * b + 1];
    const float h0 = head_point[2 * b];
    const float h1 = head_point[2 * b + 1];

    const float xyn2 = x0 * x0 + x1 * x1;  // same op order as reference
    const float xyn  = sqrtf(xyn2);
    const float K    = T2 * xyn2;          // zero-test: num^2 > K * d2

    float4* const outb = reinterpret_cast<float4*>(out) + (size_t)b * IMG4;

    for (int rem = threadIdx.x; rem < IMG4; rem += 256) {
        int i  = rem / ROW4;               // row (y) — magic-mul div by 56
        int k0 = (rem - i * ROW4) * 4;     // first column (x) of this float4

        float dy   = (float)i - h1;
        float dy2  = dy * dy;
        float dyx1 = dy * x1;

        // --- cheap classification: could any of my 4 pixels be nonzero? ---
        float numv[4], d2v[4];
        bool pred = false;
#pragma unroll
        for (int j = 0; j < 4; ++j) {
            float dx = (float)(k0 + j) - h0;
            float nu = dx * x0 + dyx1;     // mul, add (contract off) — as ref
            float d2 = dx * dx + dy2;
            numv[j] = nu;
            d2v[j]  = d2;
            pred = pred || (nu > 0.0f && nu * nu > K * d2);
        }

        float4 r;
        if (__any(pred)) {
            float* rp = &r.x;
#pragma unroll
            for (int j = 0; j < 4; ++j) {
                float an    = sqrtf(d2v[j]);          // IEEE (matches baseline)
                float denom = an * xyn;
                float dsel  = (denom > 0.0f) ? denom : 1.0f;
                float c     = numv[j] / dsel;         // IEEE div (matches baseline)
                float u     = 1.0f - c;               // exact for c in [0.5,2]
                // acos(1-u) ~= sqrt(2u) * (1 + u/12 + 3u^2/160); u<0 -> NaN
                float s     = __builtin_amdgcn_sqrtf(u + u);   // raw v_sqrt_f32
                float poly  = fmaf(u, fmaf(u, 0.01875f, 0.08333333333333333f), 1.0f);
                float theta = s * poly;
                float m     = fmaf(theta, -SCALE, 1.0f);
                rp[j] = fmaxf(m, 0.0f);               // NaN -> 0 (nan_to_num)
            }
        } else {
            r = make_float4(0.0f, 0.0f, 0.0f, 0.0f);
        }

        outb[rem] = r;                     // coalesced 1 KB/wave stores
    }
}

extern "C" void kernel_launch(void* const* d_in, const int* in_sizes, int n_in,
                              void* d_out, int out_size, void* d_ws, size_t ws_size,
                              hipStream_t stream) {
    const float* xy = (const float*)d_in[0];
    const float* hp = (const float*)d_in[1];
    float* out      = (float*)d_out;

    const int B = in_sizes[0] / 2;   // 1024

    gaze_cone_kernel<<<B, 256, 0, stream>>>(xy, hp, out);
}

// Round 11
// 208.835 us; speedup vs baseline: 1.1452x; 1.0832x over previous
//
#include <hip/hip_runtime.h>

// Problem constants
#define HW    224
#define IMG   (HW * HW)     // 50176 px per image
#define IMG4  (IMG / 4)     // 12544 float4 per image
#define TILES 49            // 7x7 tiles of 32x32 px per image

// mask = max(1 - (12/pi)*acos(c), 0), nonzero only inside a 30-deg wedge (~8% of px).
// Round-9 lesson: acosf was NOT dominant (-13us only). Row-strip waves intersect the
// wedge ~45% of the time and per-pixel classification taxes every wave. This round:
// 2D wave tiles (32 wide x 8 tall) + wave-level SAT test (cone vs AABB, widened to
// 15.1 deg + 1px margin -> conservative superset of nonzero region). Zero waves:
// ~15 instrs (store-only). Slow waves: the EXACT round-9 math, bit-identical
// (contract-off mul/add num, IEEE sqrtf, mul, IEEE div, series acos, fmaxf NaN->0),
// so output is bit-identical to the passing round-9 kernel (absmax 0.001953125).
// Slow-but-outside pixels: c < 0.9659 -> series mask <= -4e-4 -> fmaxf -> +0.0f,
// same bits as the zero path.

__global__ __launch_bounds__(256) void gaze_cone_kernel(
    const float* __restrict__ xy,          // [B,2] gaze direction
    const float* __restrict__ head_point,  // [B,2] pixel coords
    float* __restrict__ out)               // [B,1,224,224]
{
#pragma clang fp contract(off)
    const float SCALE = 3.81971863420548805845f;  // 12/pi
    const float CPHI  = 0.965474f;                // cos(15.1 deg)  (test cone, wider than 15)
    const float SPHI  = 0.260505f;                // sin(15.1 deg)

    const int bid = blockIdx.x;
    const int b   = bid / TILES;           // image
    const int t   = bid - b * TILES;       // tile 0..48
    const int tx  = t % 7;
    const int ty  = t / 7;

    const int tid = threadIdx.x;
    const int w   = tid >> 6;              // wave 0..3 (8 rows each)
    const int l   = tid & 63;

    const int row = ty * 32 + w * 8 + (l >> 3);   // global row i
    const int c4  = tx * 8 + (l & 7);             // global float4-col (0..55)
    const int k0  = c4 << 2;                      // global px col

    // Per-image scalars (uniform within block).
    const float x0 = xy[2 * b];
    const float x1 = xy[2 * b + 1];
    const float h0 = head_point[2 * b];
    const float h1 = head_point[2 * b + 1];

    // ---- wave-level SAT: does the 15.1deg cone from (h0,h1) hit this wave's
    // 32x8 tile (expanded by 1 px)?  Cone edges u-/u+ = g rotated -/+15.1deg.
    const float upx = x0 * CPHI - x1 * SPHI;   // u+
    const float upy = x0 * SPHI + x1 * CPHI;
    const float umx = x0 * CPHI + x1 * SPHI;   // u-
    const float umy = x1 * CPHI - x0 * SPHI;

    const float bx0 = (float)(tx * 32 - 1);
    const float bx1 = (float)(tx * 32 + 32);
    const float by0 = (float)(ty * 32 + w * 8 - 1);
    const float by1 = (float)(ty * 32 + w * 8 + 8);

    // Inward edge normals: n1 = perp(u-) = (-umy, umx); n2 = (upy, -upx).
    const float n1x = -umy, n1y = umx;
    const float n2x = upy,  n2y = -upx;

    // max over expanded-box corners of n.(c - h)  (branchless via fmaxf)
    const float md1 = fmaxf(n1x * bx0, n1x * bx1) + fmaxf(n1y * by0, n1y * by1)
                    - (n1x * h0 + n1y * h1);
    const float md2 = fmaxf(n2x * bx0, n2x * bx1) + fmaxf(n2y * by0, n2y * by1)
                    - (n2x * h0 + n2y * h1);

    bool sep = (md1 < 0.0f) || (md2 < 0.0f);
    // Axis-aligned separations (cone x/y extent is one-sided iff both edge dirs agree)
    sep = sep || (umx >= 0.0f && upx >= 0.0f && bx1 < h0);
    sep = sep || (umx <= 0.0f && upx <= 0.0f && bx0 > h0);
    sep = sep || (umy >= 0.0f && upy >= 0.0f && by1 < h1);
    sep = sep || (umy <= 0.0f && upy <= 0.0f && by0 > h1);

    float4 r;
    if (sep) {
        // Wave tile provably outside the cone: mask is exactly +0.0f.
        r = make_float4(0.0f, 0.0f, 0.0f, 0.0f);
    } else {
        // ---- exact round-9 math, bit-identical op order ----
        const float xyn = sqrtf(x0 * x0 + x1 * x1);
        const float dy   = (float)row - h1;
        const float dy2  = dy * dy;
        const float dyx1 = dy * x1;

        float* rp = &r.x;
#pragma unroll
        for (int j = 0; j < 4; ++j) {
            float dx    = (float)(k0 + j) - h0;
            float num   = dx * x0 + dyx1;          // mul, add (contract off)
            float d2    = dx * dx + dy2;
            float an    = sqrtf(d2);               // IEEE sqrt
            float denom = an * xyn;
            float dsel  = (denom > 0.0f) ? denom : 1.0f;
            float c     = num / dsel;              // IEEE div
            float u     = 1.0f - c;                // exact (Sterbenz)
            // acos(1-u) ~= sqrt(2u)*(1 + u/12 + 3u^2/160); u<0 -> NaN -> 0
            float s     = __builtin_amdgcn_sqrtf(u + u);
            float poly  = fmaf(u, fmaf(u, 0.01875f, 0.08333333333333333f), 1.0f);
            float theta = s * poly;
            float m     = fmaf(theta, -SCALE, 1.0f);
            rp[j] = fmaxf(m, 0.0f);                // NaN/neg -> +0.0f
        }
    }

    reinterpret_cast<float4*>(out)[(size_t)b * IMG4 + row * 56 + c4] = r;
}

extern "C" void kernel_launch(void* const* d_in, const int* in_sizes, int n_in,
                              void* d_out, int out_size, void* d_ws, size_t ws_size,
                              hipStream_t stream) {
    const float* xy = (const float*)d_in[0];
    const float* hp = (const float*)d_in[1];
    float* out      = (float*)d_out;

    const int B = in_sizes[0] / 2;   // 1024

    // One 32x32 tile per block (4 waves of 32x8), 1 float4/thread, no loop.
    gaze_cone_kernel<<<B * TILES, 256, 0, stream>>>(xy, hp, out);
}